// Round 4
// baseline (170.108 us; speedup 1.0000x reference)
//
#include <hip/hip_runtime.h>
#include <math.h>

#define B_   8
#define C_   64
#define CK_  8
#define L_   4096
#define NSPL 4       // l-split factor (blocks per (b,mb))
#define NPART 4      // partials per (b,mb) = NSPL (waves split m, not l)

typedef __attribute__((ext_vector_type(8))) __bf16 bf16x8;
typedef __attribute__((ext_vector_type(4))) __bf16 bf16x4;
typedef __attribute__((ext_vector_type(4))) float  f32x4;
typedef __attribute__((ext_vector_type(4))) short  s16x4;

// ---------------- Kernel 1: QKV projection -> bf16 ----------------
// x: [B,C,L] fp32 -> q: [B,L,8] ; kT: [B,L,8] ; vpack: fragment-major V
// vpack layout: [b][tile t=l/64][cb*4+seg][lane=quad*16+l16][i0..3]
//   element (c = cb*16+l16, l = t*64 + seg*16 + quad*4 + i)
// so attn's PV A-fragment load is one fully-coalesced 8B/lane read.
__global__ __launch_bounds__(256) void qkv_kernel(
    const float* __restrict__ x,
    const float* __restrict__ Wq, const float* __restrict__ bq,
    const float* __restrict__ Wk, const float* __restrict__ bk,
    const float* __restrict__ Wv, const float* __restrict__ bv,
    __bf16* __restrict__ qo, __bf16* __restrict__ ko, __bf16* __restrict__ vpack)
{
    __shared__ float LWq[CK_ * C_];
    __shared__ float LWk[CK_ * C_];
    __shared__ float LWv[C_ * C_];      // row-major [c_out][c_in]
    __shared__ __bf16 Lqs[64 * 8];
    __shared__ __bf16 Lks[64 * 8];

    const int tid = threadIdx.x;
    if (tid < 128) {
        ((float4*)LWq)[tid] = ((const float4*)Wq)[tid];
        ((float4*)LWk)[tid] = ((const float4*)Wk)[tid];
    }
    #pragma unroll
    for (int j = 0; j < 4; ++j)
        ((float4*)LWv)[tid + j * 256] = ((const float4*)Wv)[tid + j * 256];
    __syncthreads();

    const int b  = blockIdx.x >> 6;
    const int t  = blockIdx.x & 63;
    const int l0 = t << 6;
    const int lg = tid & 15;
    const int g  = tid >> 4;

    float va[4][4];
    float qk[4];
    #pragma unroll
    for (int j = 0; j < 4; ++j) {
        float bb = bv[4 * g + j];
        va[j][0] = bb; va[j][1] = bb; va[j][2] = bb; va[j][3] = bb;
    }
    {
        float bb = (g < 8) ? bq[g] : bk[g - 8];
        qk[0] = bb; qk[1] = bb; qk[2] = bb; qk[3] = bb;
    }
    const float* wqk = (g < 8) ? (LWq + g * C_) : (LWk + (g - 8) * C_);

    const float* xp = x + ((size_t)b * C_) * L_ + l0 + lg * 4;
    #pragma unroll 4
    for (int c4 = 0; c4 < 16; ++c4) {
        float4 xv[4];
        #pragma unroll
        for (int u = 0; u < 4; ++u)
            xv[u] = *(const float4*)(xp + (size_t)(4 * c4 + u) * L_);
        #pragma unroll
        for (int j = 0; j < 4; ++j) {
            float4 wv = ((const float4*)(LWv + (4 * g + j) * C_))[c4];
            float* a = va[j];
            a[0]=fmaf(wv.x,xv[0].x,a[0]); a[1]=fmaf(wv.x,xv[0].y,a[1]); a[2]=fmaf(wv.x,xv[0].z,a[2]); a[3]=fmaf(wv.x,xv[0].w,a[3]);
            a[0]=fmaf(wv.y,xv[1].x,a[0]); a[1]=fmaf(wv.y,xv[1].y,a[1]); a[2]=fmaf(wv.y,xv[1].z,a[2]); a[3]=fmaf(wv.y,xv[1].w,a[3]);
            a[0]=fmaf(wv.z,xv[2].x,a[0]); a[1]=fmaf(wv.z,xv[2].y,a[1]); a[2]=fmaf(wv.z,xv[2].z,a[2]); a[3]=fmaf(wv.z,xv[2].w,a[3]);
            a[0]=fmaf(wv.w,xv[3].x,a[0]); a[1]=fmaf(wv.w,xv[3].y,a[1]); a[2]=fmaf(wv.w,xv[3].z,a[2]); a[3]=fmaf(wv.w,xv[3].w,a[3]);
        }
        {
            float4 wv = ((const float4*)wqk)[c4];
            qk[0]=fmaf(wv.x,xv[0].x,qk[0]); qk[1]=fmaf(wv.x,xv[0].y,qk[1]); qk[2]=fmaf(wv.x,xv[0].z,qk[2]); qk[3]=fmaf(wv.x,xv[0].w,qk[3]);
            qk[0]=fmaf(wv.y,xv[1].x,qk[0]); qk[1]=fmaf(wv.y,xv[1].y,qk[1]); qk[2]=fmaf(wv.y,xv[1].z,qk[2]); qk[3]=fmaf(wv.y,xv[1].w,qk[3]);
            qk[0]=fmaf(wv.z,xv[2].x,qk[0]); qk[1]=fmaf(wv.z,xv[2].y,qk[1]); qk[2]=fmaf(wv.z,xv[2].z,qk[2]); qk[3]=fmaf(wv.z,xv[2].w,qk[3]);
            qk[0]=fmaf(wv.w,xv[3].x,qk[0]); qk[1]=fmaf(wv.w,xv[3].y,qk[1]); qk[2]=fmaf(wv.w,xv[3].z,qk[2]); qk[3]=fmaf(wv.w,xv[3].w,qk[3]);
        }
    }

    // vpack stores: fragment-major. thread (g,lg) holds c=4g+j, l=l0+4lg+u:
    //   cb=g>>2, l16=(g&3)*4+j, seg=lg>>2, quad=lg&3, i=u -> 8B contiguous per j
    {
        __bf16* vt = vpack + ((size_t)b * 64 + t) * 4096;
        const int cb  = g >> 2;
        const int seg = lg >> 2;
        const int qd  = lg & 3;
        #pragma unroll
        for (int j = 0; j < 4; ++j) {
            bf16x4 vv;
            vv[0]=(__bf16)va[j][0]; vv[1]=(__bf16)va[j][1]; vv[2]=(__bf16)va[j][2]; vv[3]=(__bf16)va[j][3];
            *(bf16x4*)(vt + (((cb * 4 + seg) * 64 + qd * 16 + (g & 3) * 4 + j) * 4)) = vv;
        }
    }
    // q/k: gather through LDS, then b128 stores
    #pragma unroll
    for (int u = 0; u < 4; ++u) {
        if (g < 8) Lqs[(lg * 4 + u) * 8 + g]       = (__bf16)qk[u];
        else       Lks[(lg * 4 + u) * 8 + (g - 8)] = (__bf16)qk[u];
    }
    __syncthreads();
    if (tid < 64) {
        *(bf16x8*)(qo + ((size_t)b * L_ + l0 + tid) * 8) = *(bf16x8*)(Lqs + tid * 8);
        *(bf16x8*)(ko + ((size_t)b * L_ + l0 + tid) * 8) = *(bf16x8*)(Lks + tid * 8);
    }
}

// ---------------- Kernel 2: attention, m-split waves, no LDS/barriers ----
// grid: B * 64(mb) * NSPL(lq). Wave w owns m-slice [m0+w*16, +16) over
// l in [lq*1024, +1024). Per 64-l tile: 4 QK MFMAs (seg), exp via v_exp_f32,
// PV direct-feed (QK D-frag == PV B-frag of 16x16x16). csum is scalar/lane.
__global__ __launch_bounds__(256, 4) void attn_kernel(
    const __bf16* __restrict__ q, const __bf16* __restrict__ kT,
    const __bf16* __restrict__ VP,
    __bf16* __restrict__ pacc, float* __restrict__ pcs)
{
    const int tid  = threadIdx.x;
    const int w    = tid >> 6;
    const int lane = tid & 63;
    const int quad = lane >> 4;
    const int l16  = lane & 15;
    const int lq   = blockIdx.x & 3;
    const int mb   = (blockIdx.x >> 2) & 63;
    const int b    = blockIdx.x >> 8;
    const int m0   = mb << 6;

    const __bf16* qb = q  + (size_t)b * L_ * CK_;
    const __bf16* vp = VP + ((size_t)b * 64 + lq * 16) * 4096;

    // B-frag of QK: col = this wave's m (m0 + w*16 + l16), K=8 in quad0
    bf16x8 kf = {};
    if (quad == 0) kf = *(const bf16x8*)(kT + ((size_t)b * L_ + m0 + w * 16 + l16) * CK_);

    f32x4 acc[4] = {};      // 64c x 16m : acc[cb][r] -> c = cb*16+quad*4+r, m = w*16+l16
    float csum = 0.f;

    for (int lt = 0; lt < 16; ++lt) {
        const int l0 = (lq * 16 + lt) * 64;
        const __bf16* vt = vp + (size_t)lt * 4096;

        // V fragments: fully coalesced 8B/lane loads (512B/wave each)
        s16x4 vf[4][4];
        #pragma unroll
        for (int cb = 0; cb < 4; ++cb)
            #pragma unroll
            for (int sg = 0; sg < 4; ++sg)
                vf[cb][sg] = *(const s16x4*)(vt + ((cb * 4 + sg) * 64 + lane) * 4);

        bf16x8 qf[4];
        #pragma unroll
        for (int sg = 0; sg < 4; ++sg) {
            bf16x8 tq = {};
            if (quad == 0) tq = *(const bf16x8*)(qb + (size_t)(l0 + sg * 16 + l16) * CK_);
            qf[sg] = tq;
        }

        #pragma unroll
        for (int sg = 0; sg < 4; ++sg) {
            f32x4 s = __builtin_amdgcn_mfma_f32_16x16x32_bf16(qf[sg], kf, (f32x4){0.f,0.f,0.f,0.f}, 0, 0, 0);
            // exp(x) = 2^(x*log2e) via v_exp_f32 (guaranteed fast path)
            float e0, e1, e2, e3;
            {
                float a0 = s[0] * 1.44269504088896f;
                float a1 = s[1] * 1.44269504088896f;
                float a2 = s[2] * 1.44269504088896f;
                float a3 = s[3] * 1.44269504088896f;
                asm("v_exp_f32 %0, %1" : "=v"(e0) : "v"(a0));
                asm("v_exp_f32 %0, %1" : "=v"(e1) : "v"(a1));
                asm("v_exp_f32 %0, %1" : "=v"(e2) : "v"(a2));
                asm("v_exp_f32 %0, %1" : "=v"(e3) : "v"(a3));
            }
            csum += (e0 + e1) + (e2 + e3);
            bf16x4 pk;
            pk[0] = (__bf16)e0; pk[1] = (__bf16)e1; pk[2] = (__bf16)e2; pk[3] = (__bf16)e3;
            s16x4 pb = __builtin_bit_cast(s16x4, pk);
            #pragma unroll
            for (int cb = 0; cb < 4; ++cb)
                acc[cb] = __builtin_amdgcn_mfma_f32_16x16x16bf16_1k(vf[cb][sg], pb, acc[cb], 0, 0, 0);
        }
    }

    // csum: reduce over quads (lanes with same l16 hold same m, different l)
    csum += __shfl_xor(csum, 16);
    csum += __shfl_xor(csum, 32);

    const size_t pbase = ((size_t)b * 64 + mb) * NPART + lq;
    if (quad == 0) pcs[pbase * 64 + w * 16 + l16] = csum;

    __bf16* pa = pacc + pbase * 4096;
    #pragma unroll
    for (int cb = 0; cb < 4; ++cb)
        #pragma unroll
        for (int r = 0; r < 4; ++r)
            pa[(cb * 16 + quad * 4 + r) * 64 + w * 16 + l16] = (__bf16)acc[cb][r];
}

// ---------------- Kernel 3: combine partials, normalize, residual ---------
__global__ __launch_bounds__(256) void combine_kernel(
    const __bf16* __restrict__ pacc, const float* __restrict__ pcs,
    const float* __restrict__ x, const float* __restrict__ gamma_p,
    float* __restrict__ out)
{
    const int tid = threadIdx.x;
    const int m  = tid & 63;
    const int cq = tid >> 6;
    const int b  = blockIdx.x >> 6;
    const int mb = blockIdx.x & 63;

    const size_t base = ((size_t)b * 64 + mb) * NPART;
    float csv = 0.0f;
    #pragma unroll
    for (int p = 0; p < NPART; ++p) csv += pcs[(base + p) * 64 + m];
    const float rinv = gamma_p[0] / csv;

    const __bf16* pa = pacc + base * (64 * 64);
    #pragma unroll
    for (int ci = 0; ci < 16; ++ci) {
        const int c = cq * 16 + ci;
        float s = 0.0f;
        #pragma unroll
        for (int p = 0; p < NPART; ++p)
            s += (float)pa[((size_t)p * 64 + c) * 64 + m];
        const size_t idx = ((size_t)b * C_ + c) * L_ + mb * 64 + m;
        out[idx] = fmaf(rinv, s, x[idx]);
    }
}

extern "C" void kernel_launch(void* const* d_in, const int* in_sizes, int n_in,
                              void* d_out, int out_size, void* d_ws, size_t ws_size,
                              hipStream_t stream) {
    const float* x  = (const float*)d_in[0];
    const float* Wq = (const float*)d_in[1];
    const float* bq = (const float*)d_in[2];
    const float* Wk = (const float*)d_in[3];
    const float* bk = (const float*)d_in[4];
    const float* Wv = (const float*)d_in[5];
    const float* bv = (const float*)d_in[6];
    const float* gm = (const float*)d_in[7];
    float* out = (float*)d_out;

    __bf16* ws    = (__bf16*)d_ws;
    __bf16* qo    = ws;                         // 262144 bf16
    __bf16* ko    = ws + 262144;                // 262144 bf16
    __bf16* vpack = ws + 524288;                // 2097152 bf16
    __bf16* pacc  = ws + 2621440;               // 8*64*4*4096 = 8388608 bf16
    float*  pcs   = (float*)(ws + 11010048);    // 8*64*4*64 = 131072 f32

    qkv_kernel<<<dim3(B_ * (L_ / 64)), dim3(256), 0, stream>>>(
        x, Wq, bq, Wk, bk, Wv, bv, qo, ko, vpack);
    attn_kernel<<<dim3(B_ * 64 * NSPL), dim3(256), 0, stream>>>(
        qo, ko, vpack, pacc, pcs);
    combine_kernel<<<dim3(B_ * 64), dim3(256), 0, stream>>>(
        pacc, pcs, x, gm, out);
}

// Round 7
// 132.680 us; speedup vs baseline: 1.2821x; 1.2821x over previous
//
#include <hip/hip_runtime.h>
#include <math.h>

#define B_   8
#define C_   64
#define CK_  8
#define L_   4096

typedef __attribute__((ext_vector_type(8))) __bf16 bf16x8;
typedef __attribute__((ext_vector_type(4))) __bf16 bf16x4;
typedef __attribute__((ext_vector_type(4))) float  f32x4;
typedef __attribute__((ext_vector_type(4))) short  s16x4;

// ---------------- Kernel 1: QKV projection -> bf16 ----------------
// x: [B,C,L] fp32 -> q: [B,L,8] ; kT: [B,L,8] ;
// vpack: per 64-l tile t, layout [cb*4+sg][lane=quad*16+l16][i0..3] where
// element (c = cb*16+l16, l = t*64 + sg*16 + quad*4 + i). Matches attn's
// LDS consumption order exactly, so staging is a straight linear copy.
// (identical to the r4 hardware-verified version)
__global__ __launch_bounds__(256) void qkv_kernel(
    const float* __restrict__ x,
    const float* __restrict__ Wq, const float* __restrict__ bq,
    const float* __restrict__ Wk, const float* __restrict__ bk,
    const float* __restrict__ Wv, const float* __restrict__ bv,
    __bf16* __restrict__ qo, __bf16* __restrict__ ko, __bf16* __restrict__ vpack)
{
    __shared__ float LWq[CK_ * C_];
    __shared__ float LWk[CK_ * C_];
    __shared__ float LWv[C_ * C_];      // row-major [c_out][c_in]
    __shared__ __bf16 Lqs[64 * 8];
    __shared__ __bf16 Lks[64 * 8];

    const int tid = threadIdx.x;
    if (tid < 128) {
        ((float4*)LWq)[tid] = ((const float4*)Wq)[tid];
        ((float4*)LWk)[tid] = ((const float4*)Wk)[tid];
    }
    #pragma unroll
    for (int j = 0; j < 4; ++j)
        ((float4*)LWv)[tid + j * 256] = ((const float4*)Wv)[tid + j * 256];
    __syncthreads();

    const int b  = blockIdx.x >> 6;
    const int t  = blockIdx.x & 63;
    const int l0 = t << 6;
    const int lg = tid & 15;
    const int g  = tid >> 4;

    float va[4][4];
    float qk[4];
    #pragma unroll
    for (int j = 0; j < 4; ++j) {
        float bb = bv[4 * g + j];
        va[j][0] = bb; va[j][1] = bb; va[j][2] = bb; va[j][3] = bb;
    }
    {
        float bb = (g < 8) ? bq[g] : bk[g - 8];
        qk[0] = bb; qk[1] = bb; qk[2] = bb; qk[3] = bb;
    }
    const float* wqk = (g < 8) ? (LWq + g * C_) : (LWk + (g - 8) * C_);

    const float* xp = x + ((size_t)b * C_) * L_ + l0 + lg * 4;
    #pragma unroll 4
    for (int c4 = 0; c4 < 16; ++c4) {
        float4 xv[4];
        #pragma unroll
        for (int u = 0; u < 4; ++u)
            xv[u] = *(const float4*)(xp + (size_t)(4 * c4 + u) * L_);
        #pragma unroll
        for (int j = 0; j < 4; ++j) {
            float4 wv = ((const float4*)(LWv + (4 * g + j) * C_))[c4];
            float* a = va[j];
            a[0]=fmaf(wv.x,xv[0].x,a[0]); a[1]=fmaf(wv.x,xv[0].y,a[1]); a[2]=fmaf(wv.x,xv[0].z,a[2]); a[3]=fmaf(wv.x,xv[0].w,a[3]);
            a[0]=fmaf(wv.y,xv[1].x,a[0]); a[1]=fmaf(wv.y,xv[1].y,a[1]); a[2]=fmaf(wv.y,xv[1].z,a[2]); a[3]=fmaf(wv.y,xv[1].w,a[3]);
            a[0]=fmaf(wv.z,xv[2].x,a[0]); a[1]=fmaf(wv.z,xv[2].y,a[1]); a[2]=fmaf(wv.z,xv[2].z,a[2]); a[3]=fmaf(wv.z,xv[2].w,a[3]);
            a[0]=fmaf(wv.w,xv[3].x,a[0]); a[1]=fmaf(wv.w,xv[3].y,a[1]); a[2]=fmaf(wv.w,xv[3].z,a[2]); a[3]=fmaf(wv.w,xv[3].w,a[3]);
        }
        {
            float4 wv = ((const float4*)wqk)[c4];
            qk[0]=fmaf(wv.x,xv[0].x,qk[0]); qk[1]=fmaf(wv.x,xv[0].y,qk[1]); qk[2]=fmaf(wv.x,xv[0].z,qk[2]); qk[3]=fmaf(wv.x,xv[0].w,qk[3]);
            qk[0]=fmaf(wv.y,xv[1].x,qk[0]); qk[1]=fmaf(wv.y,xv[1].y,qk[1]); qk[2]=fmaf(wv.y,xv[1].z,qk[2]); qk[3]=fmaf(wv.y,xv[1].w,qk[3]);
            qk[0]=fmaf(wv.z,xv[2].x,qk[0]); qk[1]=fmaf(wv.z,xv[2].y,qk[1]); qk[2]=fmaf(wv.z,xv[2].z,qk[2]); qk[3]=fmaf(wv.z,xv[2].w,qk[3]);
            qk[0]=fmaf(wv.w,xv[3].x,qk[0]); qk[1]=fmaf(wv.w,xv[3].y,qk[1]); qk[2]=fmaf(wv.w,xv[3].z,qk[2]); qk[3]=fmaf(wv.w,xv[3].w,qk[3]);
        }
    }

    // vpack stores: thread (g,lg) holds c=4g+j, l=l0+4lg+u.
    // cb=g>>2, l16=(g&3)*4+j, sg=lg>>2, quad=lg&3, i=u.
    {
        __bf16* vt = vpack + ((size_t)b * 64 + t) * 4096;
        const int cb = g >> 2;
        const int sg = lg >> 2;
        const int qd = lg & 3;
        #pragma unroll
        for (int j = 0; j < 4; ++j) {
            bf16x4 vv;
            vv[0]=(__bf16)va[j][0]; vv[1]=(__bf16)va[j][1]; vv[2]=(__bf16)va[j][2]; vv[3]=(__bf16)va[j][3];
            *(bf16x4*)(vt + ((size_t)((cb * 4 + sg) * 64 + qd * 16 + (g & 3) * 4 + j)) * 4) = vv;
        }
    }
    // q/k: gather through LDS, then b128 stores
    #pragma unroll
    for (int u = 0; u < 4; ++u) {
        if (g < 8) Lqs[(lg * 4 + u) * 8 + g]       = (__bf16)qk[u];
        else       Lks[(lg * 4 + u) * 8 + (g - 8)] = (__bf16)qk[u];
    }
    __syncthreads();
    if (tid < 64) {
        *(bf16x8*)(qo + ((size_t)b * L_ + l0 + tid) * 8) = *(bf16x8*)(Lqs + tid * 8);
        *(bf16x8*)(ko + ((size_t)b * L_ + l0 + tid) * 8) = *(bf16x8*)(Lks + tid * 8);
    }
}

// ---------------- Kernel 2: fused attention ------------------------------
// grid: B*64 (b,mb) x 512 thr (8 waves: wh=w&3 m-slice, lh=w>>2 l-half).
// Reg-staged double-buffered V in LDS (T14): after the step-s barrier each
// wave issues its global loads for step s+1 into VGPRs (latency hidden under
// the compute phase), then ds_writes them into buf (s+1)&1 at the end of the
// step. One barrier per step; dbuf race-free; barrier publishes ds_writes.
// exp via __expf on the MFMA result (compiler-handled MFMA->VALU hazard;
// inline-asm v_exp reading the MFMA dest directly was the r5/r6 NaN suspect).
// P feeds PV in-register (QK 16x16x32 D-frag == PV 16x16x16 B-frag).
// End: lh-pair reduce via dedicated Sc scratch, normalize, +x, write out.
__global__ __launch_bounds__(512, 4) void attn_kernel(
    const __bf16* __restrict__ q, const __bf16* __restrict__ kT,
    const __bf16* __restrict__ VP, const float* __restrict__ x,
    const float* __restrict__ gamma_p, float* __restrict__ out)
{
    __shared__ __bf16 Lv[2][2][4096];   // [buf][lh-tile][8KB tile]
    __shared__ float  Sc[4096];         // dedicated epilogue scratch (16 KB)
    __shared__ float  csA[8][16];

    const int tid  = threadIdx.x;
    const int w    = tid >> 6;
    const int lane = tid & 63;
    const int quad = lane >> 4;
    const int l16  = lane & 15;
    const int wh   = w & 3;
    const int lh   = w >> 2;
    const int mb   = blockIdx.x & 63;
    const int b    = blockIdx.x >> 6;
    const int m0   = mb << 6;

    const __bf16* vp = VP + (size_t)b * (64 * 4096);
    const __bf16* qb = q  + (size_t)b * L_ * CK_;

    bf16x8 kf = {};
    if (quad == 0) kf = *(const bf16x8*)(kT + ((size_t)b * L_ + m0 + wh * 16 + l16) * CK_);

    // stage shares: wave w stages shares {2w, 2w+1} of 16 (2 tiles x 8 segs)
    const int tA = (w * 2) >> 3,     sA = (w * 2) & 7;
    const int tB = (w * 2 + 1) >> 3, sB = (w * 2 + 1) & 7;
    const __bf16* gA = vp + (size_t)(tA * 32) * 4096 + sA * 512 + lane * 8;
    const __bf16* gB = vp + (size_t)(tB * 32) * 4096 + sB * 512 + lane * 8;
    const int dA = sA * 512 + lane * 8;
    const int dB = sB * 512 + lane * 8;

    f32x4 acc[4] = {};
    float csum = 0.f;
    bf16x8 qc[4], qn[4];
    bf16x8 rA, rB;

    // prologue: stage step 0 into buf0 via regs; load qf(0)
    rA = *(const bf16x8*)gA;
    rB = *(const bf16x8*)gB;
    *(bf16x8*)(&Lv[0][tA][dA]) = rA;
    *(bf16x8*)(&Lv[0][tB][dB]) = rB;
    #pragma unroll
    for (int sg = 0; sg < 4; ++sg) {
        bf16x8 tq = {};
        if (quad == 0) tq = *(const bf16x8*)(qb + (size_t)((lh * 32) * 64 + sg * 16 + l16) * CK_);
        qc[sg] = tq;
    }

    for (int s = 0; s < 32; ++s) {
        __syncthreads();    // publish Lv[s&1]; protects buf (s+1)&1 overwrite

        if (s + 1 < 32) {   // issue next-step loads early (hidden under compute)
            rA = *(const bf16x8*)(gA + (size_t)(s + 1) * 4096);
            rB = *(const bf16x8*)(gB + (size_t)(s + 1) * 4096);
            #pragma unroll
            for (int sg = 0; sg < 4; ++sg) {
                bf16x8 tq = {};
                if (quad == 0) tq = *(const bf16x8*)(qb + (size_t)((lh * 32 + s + 1) * 64 + sg * 16 + l16) * CK_);
                qn[sg] = tq;
            }
        }

        const __bf16* Lb = &Lv[s & 1][lh][0];
        #pragma unroll
        for (int sg = 0; sg < 4; ++sg) {
            f32x4 sv = __builtin_amdgcn_mfma_f32_16x16x32_bf16(qc[sg], kf, (f32x4){0.f,0.f,0.f,0.f}, 0, 0, 0);
            const float e0 = __expf(sv[0]);
            const float e1 = __expf(sv[1]);
            const float e2 = __expf(sv[2]);
            const float e3 = __expf(sv[3]);
            csum += (e0 + e1) + (e2 + e3);
            bf16x4 pk;
            pk[0] = (__bf16)e0; pk[1] = (__bf16)e1; pk[2] = (__bf16)e2; pk[3] = (__bf16)e3;
            s16x4 pb = __builtin_bit_cast(s16x4, pk);
            #pragma unroll
            for (int cb = 0; cb < 4; ++cb) {
                s16x4 vf = *(const s16x4*)(Lb + ((size_t)((cb * 4 + sg) * 64 + lane)) * 4);
                acc[cb] = __builtin_amdgcn_mfma_f32_16x16x16bf16_1k(vf, pb, acc[cb], 0, 0, 0);
            }
        }

        if (s + 1 < 32) {   // write-late into the other buffer
            const int nb = (s + 1) & 1;
            *(bf16x8*)(&Lv[nb][tA][dA]) = rA;
            *(bf16x8*)(&Lv[nb][tB][dB]) = rB;
        }
        #pragma unroll
        for (int sg = 0; sg < 4; ++sg) qc[sg] = qn[sg];
    }

    // ---- epilogue: reduce lh=1 into lh=0 via Sc, normalize, residual ----
    if (lh == 1) {
        #pragma unroll
        for (int cb = 0; cb < 4; ++cb)
            #pragma unroll
            for (int r = 0; r < 4; ++r)
                Sc[(wh * 64 + cb * 16 + quad * 4 + r) * 16 + l16] = acc[cb][r];
    }
    csum += __shfl_xor(csum, 16);
    csum += __shfl_xor(csum, 32);
    if (quad == 0) csA[w][l16] = csum;
    __syncthreads();

    if (lh == 0) {
        const float rinv = gamma_p[0] / (csA[wh][l16] + csA[wh + 4][l16]);
        #pragma unroll
        for (int cb = 0; cb < 4; ++cb) {
            #pragma unroll
            for (int r = 0; r < 4; ++r) {
                const int c = cb * 16 + quad * 4 + r;
                const float vsum = acc[cb][r] + Sc[(wh * 64 + c) * 16 + l16];
                const size_t idx = ((size_t)(b * 64 + c)) * L_ + m0 + wh * 16 + l16;
                out[idx] = fmaf(rinv, vsum, x[idx]);
            }
        }
    }
}

extern "C" void kernel_launch(void* const* d_in, const int* in_sizes, int n_in,
                              void* d_out, int out_size, void* d_ws, size_t ws_size,
                              hipStream_t stream) {
    const float* x  = (const float*)d_in[0];
    const float* Wq = (const float*)d_in[1];
    const float* bq = (const float*)d_in[2];
    const float* Wk = (const float*)d_in[3];
    const float* bk = (const float*)d_in[4];
    const float* Wv = (const float*)d_in[5];
    const float* bv = (const float*)d_in[6];
    const float* gm = (const float*)d_in[7];
    float* out = (float*)d_out;

    __bf16* ws    = (__bf16*)d_ws;
    __bf16* qo    = ws;                         // 262144 bf16
    __bf16* ko    = ws + 262144;                // 262144 bf16
    __bf16* vpack = ws + 524288;                // 2097152 bf16

    qkv_kernel<<<dim3(B_ * (L_ / 64)), dim3(256), 0, stream>>>(
        x, Wq, bq, Wk, bk, Wv, bv, qo, ko, vpack);
    attn_kernel<<<dim3(B_ * 64), dim3(512), 0, stream>>>(
        qo, ko, vpack, x, gm, out);
}

// Round 8
// 126.802 us; speedup vs baseline: 1.3415x; 1.0464x over previous
//
#include <hip/hip_runtime.h>
#include <math.h>

#define B_   8
#define C_   64
#define CK_  8
#define L_   4096

typedef __attribute__((ext_vector_type(8))) __bf16 bf16x8;
typedef __attribute__((ext_vector_type(4))) __bf16 bf16x4;
typedef __attribute__((ext_vector_type(4))) float  f32x4;

// ---------------- Kernel 1: QKV projection -> bf16 ----------------
// x: [B,C,L] fp32 -> q: [B,L,8] ; kT: [B,L,8] ;
// vpack: per 64-l tile t, layout [cb*4+sg][lane=quad*16+l16][i0..3] where
// element (c = cb*16+l16, l = t*64 + sg*16 + quad*4 + i).
// (byte-identical to the r7 hardware-verified version)
__global__ __launch_bounds__(256) void qkv_kernel(
    const float* __restrict__ x,
    const float* __restrict__ Wq, const float* __restrict__ bq,
    const float* __restrict__ Wk, const float* __restrict__ bk,
    const float* __restrict__ Wv, const float* __restrict__ bv,
    __bf16* __restrict__ qo, __bf16* __restrict__ ko, __bf16* __restrict__ vpack)
{
    __shared__ float LWq[CK_ * C_];
    __shared__ float LWk[CK_ * C_];
    __shared__ float LWv[C_ * C_];      // row-major [c_out][c_in]
    __shared__ __bf16 Lqs[64 * 8];
    __shared__ __bf16 Lks[64 * 8];

    const int tid = threadIdx.x;
    if (tid < 128) {
        ((float4*)LWq)[tid] = ((const float4*)Wq)[tid];
        ((float4*)LWk)[tid] = ((const float4*)Wk)[tid];
    }
    #pragma unroll
    for (int j = 0; j < 4; ++j)
        ((float4*)LWv)[tid + j * 256] = ((const float4*)Wv)[tid + j * 256];
    __syncthreads();

    const int b  = blockIdx.x >> 6;
    const int t  = blockIdx.x & 63;
    const int l0 = t << 6;
    const int lg = tid & 15;
    const int g  = tid >> 4;

    float va[4][4];
    float qk[4];
    #pragma unroll
    for (int j = 0; j < 4; ++j) {
        float bb = bv[4 * g + j];
        va[j][0] = bb; va[j][1] = bb; va[j][2] = bb; va[j][3] = bb;
    }
    {
        float bb = (g < 8) ? bq[g] : bk[g - 8];
        qk[0] = bb; qk[1] = bb; qk[2] = bb; qk[3] = bb;
    }
    const float* wqk = (g < 8) ? (LWq + g * C_) : (LWk + (g - 8) * C_);

    const float* xp = x + ((size_t)b * C_) * L_ + l0 + lg * 4;
    #pragma unroll 4
    for (int c4 = 0; c4 < 16; ++c4) {
        float4 xv[4];
        #pragma unroll
        for (int u = 0; u < 4; ++u)
            xv[u] = *(const float4*)(xp + (size_t)(4 * c4 + u) * L_);
        #pragma unroll
        for (int j = 0; j < 4; ++j) {
            float4 wv = ((const float4*)(LWv + (4 * g + j) * C_))[c4];
            float* a = va[j];
            a[0]=fmaf(wv.x,xv[0].x,a[0]); a[1]=fmaf(wv.x,xv[0].y,a[1]); a[2]=fmaf(wv.x,xv[0].z,a[2]); a[3]=fmaf(wv.x,xv[0].w,a[3]);
            a[0]=fmaf(wv.y,xv[1].x,a[0]); a[1]=fmaf(wv.y,xv[1].y,a[1]); a[2]=fmaf(wv.y,xv[1].z,a[2]); a[3]=fmaf(wv.y,xv[1].w,a[3]);
            a[0]=fmaf(wv.z,xv[2].x,a[0]); a[1]=fmaf(wv.z,xv[2].y,a[1]); a[2]=fmaf(wv.z,xv[2].z,a[2]); a[3]=fmaf(wv.z,xv[2].w,a[3]);
            a[0]=fmaf(wv.w,xv[3].x,a[0]); a[1]=fmaf(wv.w,xv[3].y,a[1]); a[2]=fmaf(wv.w,xv[3].z,a[2]); a[3]=fmaf(wv.w,xv[3].w,a[3]);
        }
        {
            float4 wv = ((const float4*)wqk)[c4];
            qk[0]=fmaf(wv.x,xv[0].x,qk[0]); qk[1]=fmaf(wv.x,xv[0].y,qk[1]); qk[2]=fmaf(wv.x,xv[0].z,qk[2]); qk[3]=fmaf(wv.x,xv[0].w,qk[3]);
            qk[0]=fmaf(wv.y,xv[1].x,qk[0]); qk[1]=fmaf(wv.y,xv[1].y,qk[1]); qk[2]=fmaf(wv.y,xv[1].z,qk[2]); qk[3]=fmaf(wv.y,xv[1].w,qk[3]);
            qk[0]=fmaf(wv.z,xv[2].x,qk[0]); qk[1]=fmaf(wv.z,xv[2].y,qk[1]); qk[2]=fmaf(wv.z,xv[2].z,qk[2]); qk[3]=fmaf(wv.z,xv[2].w,qk[3]);
            qk[0]=fmaf(wv.w,xv[3].x,qk[0]); qk[1]=fmaf(wv.w,xv[3].y,qk[1]); qk[2]=fmaf(wv.w,xv[3].z,qk[2]); qk[3]=fmaf(wv.w,xv[3].w,qk[3]);
        }
    }

    // vpack stores: thread (g,lg) holds c=4g+j, l=l0+4lg+u.
    // cb=g>>2, l16=(g&3)*4+j, sg=lg>>2, quad=lg&3, i=u.
    {
        __bf16* vt = vpack + ((size_t)b * 64 + t) * 4096;
        const int cb = g >> 2;
        const int sg = lg >> 2;
        const int qd = lg & 3;
        #pragma unroll
        for (int j = 0; j < 4; ++j) {
            bf16x4 vv;
            vv[0]=(__bf16)va[j][0]; vv[1]=(__bf16)va[j][1]; vv[2]=(__bf16)va[j][2]; vv[3]=(__bf16)va[j][3];
            *(bf16x4*)(vt + ((size_t)((cb * 4 + sg) * 64 + qd * 16 + (g & 3) * 4 + j)) * 4) = vv;
        }
    }
    // q/k: gather through LDS, then b128 stores
    #pragma unroll
    for (int u = 0; u < 4; ++u) {
        if (g < 8) Lqs[(lg * 4 + u) * 8 + g]       = (__bf16)qk[u];
        else       Lks[(lg * 4 + u) * 8 + (g - 8)] = (__bf16)qk[u];
    }
    __syncthreads();
    if (tid < 64) {
        *(bf16x8*)(qo + ((size_t)b * L_ + l0 + tid) * 8) = *(bf16x8*)(Lqs + tid * 8);
        *(bf16x8*)(ko + ((size_t)b * L_ + l0 + tid) * 8) = *(bf16x8*)(Lks + tid * 8);
    }
}

// ---------------- Kernel 2: fused attention ------------------------------
// grid: B*64 (b,mb) x 512 thr (8 waves: wh=w&3 m-slice, lh=w>>2 l-half).
// 16 iterations, each processing a PAIR of 64-l tiles per lh (4 tiles/block
// staged per iter; reg-staged double-buffered LDS, one barrier per iter).
// q loads are BROADCAST (no quad mask): kf is zero for quad!=0, so k>=8
// product terms vanish regardless of q garbage there.
// PV uses K=32 MFMA: concatenate the pair's V frags (a8) and P frags (p8);
// k-slot (quad,i) pairing is elementwise, so l_A == l_B slot-for-slot.
// End: lh-pair reduce via Lv-buf0 scratch (disjoint from last-iter buf1),
// normalize, +x, write out.
__global__ __launch_bounds__(512, 4) void attn_kernel(
    const __bf16* __restrict__ q, const __bf16* __restrict__ kT,
    const __bf16* __restrict__ VP, const float* __restrict__ x,
    const float* __restrict__ gamma_p, float* __restrict__ out)
{
    __shared__ __bf16 Lv[2][4][4096];   // 64 KB: [buf][ph*2 layout: tl=0,1 -> phase0 lh0/lh1; tl=2,3 -> phase1]
    __shared__ float  csA[8][16];

    const int tid  = threadIdx.x;
    const int w    = tid >> 6;
    const int lane = tid & 63;
    const int quad = lane >> 4;
    const int l16  = lane & 15;
    const int wh   = w & 3;
    const int lh   = w >> 2;
    const int mb   = blockIdx.x & 63;
    const int b    = blockIdx.x >> 6;
    const int m0   = mb << 6;

    const __bf16* vp = VP + (size_t)b * (64 * 4096);
    const __bf16* qb = q  + (size_t)b * L_ * CK_;

    bf16x8 kf = {};
    if (quad == 0) kf = *(const bf16x8*)(kT + ((size_t)b * L_ + m0 + wh * 16 + l16) * CK_);

    // staging shares: u = w*4+k (0..31): tl = u>>3, seg = u&7.
    // Lv tile tl holds global tile (tl&1)*32 + 2*i + (tl>>1)  [lh = tl&1, phase = tl>>1]
    const __bf16* gk[4];
    int ok[4];
    #pragma unroll
    for (int k = 0; k < 4; ++k) {
        const int u = w * 4 + k, tl = u >> 3, seg = u & 7;
        gk[k] = vp + (size_t)((tl & 1) * 32 + (tl >> 1)) * 4096 + seg * 512 + lane * 8;
        ok[k] = tl * 4096 + seg * 512 + lane * 8;
    }

    f32x4 acc[4] = {};
    float csum = 0.f;
    bf16x8 r[4];

    // prologue: stage iter 0 into buf0
    #pragma unroll
    for (int k = 0; k < 4; ++k) r[k] = *(const bf16x8*)gk[k];
    #pragma unroll
    for (int k = 0; k < 4; ++k) *(bf16x8*)(&Lv[0][0][0] + ok[k]) = r[k];

    for (int i = 0; i < 16; ++i) {
        __syncthreads();    // publish buf i&1; all reads of buf (i+1)&1 (iter i-1) done

        if (i < 15) {       // issue next-iter V loads early (land under compute)
            #pragma unroll
            for (int k = 0; k < 4; ++k)
                r[k] = *(const bf16x8*)(gk[k] + (size_t)(i + 1) * 8192);
        }

        // broadcast q loads for the pair (tiles lh*32+2i, lh*32+2i+1)
        bf16x8 qA[4], qB[4];
        #pragma unroll
        for (int sg = 0; sg < 4; ++sg) {
            qA[sg] = *(const bf16x8*)(qb + (size_t)((lh * 32 + 2 * i)     * 64 + sg * 16 + l16) * CK_);
            qB[sg] = *(const bf16x8*)(qb + (size_t)((lh * 32 + 2 * i + 1) * 64 + sg * 16 + l16) * CK_);
        }

        bf16x4 pkA[4], pkB[4];
        #pragma unroll
        for (int sg = 0; sg < 4; ++sg) {
            f32x4 sv = __builtin_amdgcn_mfma_f32_16x16x32_bf16(qA[sg], kf, (f32x4){0.f,0.f,0.f,0.f}, 0, 0, 0);
            const float e0 = __expf(sv[0]);
            const float e1 = __expf(sv[1]);
            const float e2 = __expf(sv[2]);
            const float e3 = __expf(sv[3]);
            csum += (e0 + e1) + (e2 + e3);
            pkA[sg][0]=(__bf16)e0; pkA[sg][1]=(__bf16)e1; pkA[sg][2]=(__bf16)e2; pkA[sg][3]=(__bf16)e3;
        }
        #pragma unroll
        for (int sg = 0; sg < 4; ++sg) {
            f32x4 sv = __builtin_amdgcn_mfma_f32_16x16x32_bf16(qB[sg], kf, (f32x4){0.f,0.f,0.f,0.f}, 0, 0, 0);
            const float e0 = __expf(sv[0]);
            const float e1 = __expf(sv[1]);
            const float e2 = __expf(sv[2]);
            const float e3 = __expf(sv[3]);
            csum += (e0 + e1) + (e2 + e3);
            pkB[sg][0]=(__bf16)e0; pkB[sg][1]=(__bf16)e1; pkB[sg][2]=(__bf16)e2; pkB[sg][3]=(__bf16)e3;
        }

        const __bf16* LbA = &Lv[i & 1][lh][0];
        const __bf16* LbB = &Lv[i & 1][2 + lh][0];
        #pragma unroll
        for (int sg = 0; sg < 4; ++sg) {
            bf16x8 p8 = __builtin_shufflevector(pkA[sg], pkB[sg], 0, 1, 2, 3, 4, 5, 6, 7);
            #pragma unroll
            for (int cb = 0; cb < 4; ++cb) {
                bf16x4 vfA = *(const bf16x4*)(LbA + ((size_t)((cb * 4 + sg) * 64 + lane)) * 4);
                bf16x4 vfB = *(const bf16x4*)(LbB + ((size_t)((cb * 4 + sg) * 64 + lane)) * 4);
                bf16x8 a8 = __builtin_shufflevector(vfA, vfB, 0, 1, 2, 3, 4, 5, 6, 7);
                acc[cb] = __builtin_amdgcn_mfma_f32_16x16x32_bf16(a8, p8, acc[cb], 0, 0, 0);
            }
        }

        if (i < 15) {       // write-late into the other buffer
            const int nb = (i + 1) & 1;
            #pragma unroll
            for (int k = 0; k < 4; ++k)
                *(bf16x8*)(&Lv[nb][0][0] + ok[k]) = r[k];
        }
    }

    // ---- epilogue: reduce lh=1 into lh=0, normalize, residual ----
    // Sc = first 16 KB of Lv = buf0 tiles 0-1; last iter (15) read buf1 only.
    float* Sc = (float*)&Lv[0][0][0];
    if (lh == 1) {
        #pragma unroll
        for (int cb = 0; cb < 4; ++cb)
            #pragma unroll
            for (int r2 = 0; r2 < 4; ++r2)
                Sc[(wh * 64 + cb * 16 + quad * 4 + r2) * 16 + l16] = acc[cb][r2];
    }
    csum += __shfl_xor(csum, 16);
    csum += __shfl_xor(csum, 32);
    if (quad == 0) csA[w][l16] = csum;
    __syncthreads();

    if (lh == 0) {
        const float rinv = gamma_p[0] / (csA[wh][l16] + csA[wh + 4][l16]);
        #pragma unroll
        for (int cb = 0; cb < 4; ++cb) {
            #pragma unroll
            for (int r2 = 0; r2 < 4; ++r2) {
                const int c = cb * 16 + quad * 4 + r2;
                const float vsum = acc[cb][r2] + Sc[(wh * 64 + c) * 16 + l16];
                const size_t idx = ((size_t)(b * 64 + c)) * L_ + m0 + wh * 16 + l16;
                out[idx] = fmaf(rinv, vsum, x[idx]);
            }
        }
    }
}

extern "C" void kernel_launch(void* const* d_in, const int* in_sizes, int n_in,
                              void* d_out, int out_size, void* d_ws, size_t ws_size,
                              hipStream_t stream) {
    const float* x  = (const float*)d_in[0];
    const float* Wq = (const float*)d_in[1];
    const float* bq = (const float*)d_in[2];
    const float* Wk = (const float*)d_in[3];
    const float* bk = (const float*)d_in[4];
    const float* Wv = (const float*)d_in[5];
    const float* bv = (const float*)d_in[6];
    const float* gm = (const float*)d_in[7];
    float* out = (float*)d_out;

    __bf16* ws    = (__bf16*)d_ws;
    __bf16* qo    = ws;                         // 262144 bf16
    __bf16* ko    = ws + 262144;                // 262144 bf16
    __bf16* vpack = ws + 524288;                // 2097152 bf16

    qkv_kernel<<<dim3(B_ * (L_ / 64)), dim3(256), 0, stream>>>(
        x, Wq, bq, Wk, bk, Wv, bv, qo, ko, vpack);
    attn_kernel<<<dim3(B_ * 64), dim3(512), 0, stream>>>(
        qo, ko, vpack, x, gm, out);
}